// Round 4
// baseline (81455.670 us; speedup 1.0000x reference)
//
#include <hip/hip_runtime.h>
#include <cstdint>
#include <cstddef>

// ============================================================================
// PointerNet: encoder LSTM (B=512,S=256,D=2,H=256) + autoregressive pointer
// decode with jax.random.categorical (threefry2x32 partitionable, key 42).
// Output: int32 indices [512][256], trajectory-exact vs JAX reference.
//
// R8 = R6/R7 rotated schedule with the attention pipeline in REGISTERS.
// R6/R7 failed from rule-#20 scratch demotion: the 16-phase loop didn't fully
// unroll, so eA[(ph+2)%3] kept a runtime index -> whole pipeline in scratch
// (WRITE_SIZE 75.5GB, VALUBusy 3.9%, 80ms) -- independent of VGPR budget,
// which is why launch_bounds didn't help (VGPR_Count pinned at 64 both runs).
// Fix: NO loop -- 16 phases macro-expanded, 3 chunk buffers are named structs
// (cA/cB/cC) rotated in the macro table; every index is a literal -> SROA
// keeps the pipeline in VGPRs. __launch_bounds__(1024,4) gives the 128-reg
// budget the ~124-reg live set needs (1 block/CU resident anyway: 128 blocks).
//  * schedule: attn(t) encK4 loads (L3, ~700cy) issued+consumed interleaved
//    with next step's Wh.h sweep (both need only h_t); depth-2-ahead pipeline,
//    4 waves/SIMD issue (~680cy/phase) covers the load latency.
//  * 4 barriers/decoder step; FMA order identical to R4 -> exact trajectory
//    (R6/R7 passed with absmax 0; only the storage class changes here).
// ============================================================================

typedef float v4f __attribute__((ext_vector_type(4)));

#define WS_ENCW4_OFF  (2u << 20)                    // [256 k][256 u][4 g] f32
#define WS_DECWI4_OFF (3u << 20)
#define WS_DECWH4_OFF (4u << 20)
#define WS_ENCK4_OFF  (5u << 20)                    // [512 b][64 u4][256 s][4] f32
#define WS_NEEDED     ((size_t)(5u << 20) + (size_t)512 * 64 * 256 * 16)

__device__ __forceinline__ unsigned rotl32(unsigned x, int r) {
  return (x << r) | (x >> (32 - r));
}
__device__ __forceinline__ float sigm(float x) { return 1.f / (1.f + expf(-x)); }

// Threefry-2x32, 20 rounds (jax._src.prng schedule) — verified exact R1-R7.
__device__ __forceinline__ void tf2(unsigned k0, unsigned k1,
                                    unsigned& x0, unsigned& x1) {
  const unsigned k2 = k0 ^ k1 ^ 0x1BD11BDAu;
  x0 += k0; x1 += k1;
  x0 += x1; x1 = rotl32(x1, 13); x1 ^= x0;
  x0 += x1; x1 = rotl32(x1, 15); x1 ^= x0;
  x0 += x1; x1 = rotl32(x1, 26); x1 ^= x0;
  x0 += x1; x1 = rotl32(x1,  6); x1 ^= x0;
  x0 += k1; x1 += k2 + 1u;
  x0 += x1; x1 = rotl32(x1, 17); x1 ^= x0;
  x0 += x1; x1 = rotl32(x1, 29); x1 ^= x0;
  x0 += x1; x1 = rotl32(x1, 16); x1 ^= x0;
  x0 += x1; x1 = rotl32(x1, 24); x1 ^= x0;
  x0 += k2; x1 += k0 + 2u;
  x0 += x1; x1 = rotl32(x1, 13); x1 ^= x0;
  x0 += x1; x1 = rotl32(x1, 15); x1 ^= x0;
  x0 += x1; x1 = rotl32(x1, 26); x1 ^= x0;
  x0 += x1; x1 = rotl32(x1,  6); x1 ^= x0;
  x0 += k0; x1 += k1 + 3u;
  x0 += x1; x1 = rotl32(x1, 17); x1 ^= x0;
  x0 += x1; x1 = rotl32(x1, 29); x1 ^= x0;
  x0 += x1; x1 = rotl32(x1, 16); x1 ^= x0;
  x0 += x1; x1 = rotl32(x1, 24); x1 ^= x0;
  x0 += k1; x1 += k2 + 4u;
  x0 += x1; x1 = rotl32(x1, 13); x1 ^= x0;
  x0 += x1; x1 = rotl32(x1, 15); x1 ^= x0;
  x0 += x1; x1 = rotl32(x1, 26); x1 ^= x0;
  x0 += x1; x1 = rotl32(x1,  6); x1 ^= x0;
  x0 += k2; x1 += k0 + 5u;
}

// Repack W [1024 rows][256 k] row-major -> [k][u][gate] (float4 per (k,u)).
__global__ void repack_k(const float* __restrict__ eWh,
                         const float* __restrict__ dWi,
                         const float* __restrict__ dWh,
                         float* __restrict__ ws) {
  float* encW4 = (float*)((char*)ws + WS_ENCW4_OFF);
  float* decWi4 = (float*)((char*)ws + WS_DECWI4_OFF);
  float* decWh4 = (float*)((char*)ws + WS_DECWH4_OFF);
  const int n = blockIdx.x * blockDim.x + threadIdx.x;   // 65536 = 256k x 256u
  if (n >= 65536) return;
  const int k = n >> 8, u = n & 255;
#pragma unroll
  for (int g = 0; g < 4; ++g) {
    const int src = ((g << 8) + u) * 256 + k;
    const int dst = (n << 2) + g;
    encW4[dst] = eWh[src];
    decWi4[dst] = dWi[src];
    decWh4[dst] = dWh[src];
  }
}

struct chk { v4f e0, e1, e2, e3; };                 // one 4-k4 attention chunk

__global__ void __launch_bounds__(1024, 4)
ptrnet_kernel(const float* __restrict__ inp,    // [512][256][2]
              const float* __restrict__ eWi,    // [1024][2]
              const float* __restrict__ eBi, const float* __restrict__ eBh,
              const float* __restrict__ dBi, const float* __restrict__ dBh,
              int* __restrict__ out,            // [512][256]
              float* __restrict__ ws) {
  const int tid  = threadIdx.x;
  const int wave = tid >> 6, l = tid & 63;
  const int kq   = wave >> 2;               // K-quarter 0..3 (16 k4 each)
  const int uw   = wave & 3;                // u-slice 0..3
  const int uP   = (uw << 6) | l;           // this lane's unit in P1 (matmul)
  const int k4b  = kq << 4;
  const int bA   = tid >> 8;                // this thread's batch in P2/attn
  const int uA   = tid & 255;               // this thread's unit/score in P2/attn
  const int b0   = blockIdx.x << 2;
  const int bG   = b0 + bA;

  const v4f* encW4  = (const v4f*)((char*)ws + WS_ENCW4_OFF);
  const v4f* decWi4 = (const v4f*)((char*)ws + WS_DECWI4_OFF);
  const v4f* decWh4 = (const v4f*)((char*)ws + WS_DECWH4_OFF);
  v4f* encK4 = (v4f*)((char*)ws + WS_ENCK4_OFF);

  __shared__ __align__(16) float hsF[2][1024];   // h dbuf: [buf][b*256+u]
  __shared__ __align__(16) v4f dinV[256];        // dec_in [b][64 k4]
  __shared__ __align__(16) v4f red[16][256];     // partials [kq*4+b][u] (gates)
  __shared__ unsigned char maskC[4][256];
  __shared__ float partV[4][4];
  __shared__ int   partI[4][4];

  // ---- activation-thread constants (keyed by uA) ----
  const float ebi_ = eBi[uA] + eBh[uA];
  const float ebf_ = eBi[256 + uA] + eBh[256 + uA];
  const float ebg_ = eBi[512 + uA] + eBh[512 + uA];
  const float ebo_ = eBi[768 + uA] + eBh[768 + uA];
  const float wxi0 = eWi[2 * uA], wxi1 = eWi[2 * uA + 1];
  const float wxf0 = eWi[2 * (256 + uA)], wxf1 = eWi[2 * (256 + uA) + 1];
  const float wxg0 = eWi[2 * (512 + uA)], wxg1 = eWi[2 * (512 + uA) + 1];
  const float wxo0 = eWi[2 * (768 + uA)], wxo1 = eWi[2 * (768 + uA) + 1];

  hsF[0][tid] = 0.f;
  __syncthreads();

  float c = 0.f;        // cell state for (bG, uA) — register-resident throughout
  int p = 0;

  // ---------------- encoder: 256 steps (R4-exact) ----------------
  for (int t = 0; t < 256; ++t) {
    v4f a0 = (v4f)0.f, a1 = (v4f)0.f, a2 = (v4f)0.f, a3 = (v4f)0.f;
    const v4f* Wp = encW4 + uP;
    const v4f* hq = (const v4f*)&hsF[p][0];       // [4 b][64 k4]
#pragma unroll 2
    for (int kk = 0; kk < 16; ++kk) {
      const int k4 = k4b + kk;
      const v4f w0 = Wp[(k4 * 4 + 0) << 8];
      const v4f w1 = Wp[(k4 * 4 + 1) << 8];
      const v4f w2 = Wp[(k4 * 4 + 2) << 8];
      const v4f w3 = Wp[(k4 * 4 + 3) << 8];
      const v4f h0 = hq[k4];
      const v4f h1 = hq[64 + k4];
      const v4f h2 = hq[128 + k4];
      const v4f h3 = hq[192 + k4];
      a0 += w0 * h0.x + w1 * h0.y + w2 * h0.z + w3 * h0.w;
      a1 += w0 * h1.x + w1 * h1.y + w2 * h1.z + w3 * h1.w;
      a2 += w0 * h2.x + w1 * h2.y + w2 * h2.z + w3 * h2.w;
      a3 += w0 * h3.x + w1 * h3.y + w2 * h3.z + w3 * h3.w;
    }
    red[(kq << 2) | 0][uP] = a0;
    red[(kq << 2) | 1][uP] = a1;
    red[(kq << 2) | 2][uP] = a2;
    red[(kq << 2) | 3][uP] = a3;
    __syncthreads();                              // S_B: partials ready
    const v4f gv = red[bA][uA] + red[4 + bA][uA] + red[8 + bA][uA] + red[12 + bA][uA];
    const float2 xv = *(const float2*)(inp + (((bG) << 8) + t) * 2);
    const float ai = gv.x + ebi_ + wxi0 * xv.x + wxi1 * xv.y;
    const float af = gv.y + ebf_ + wxf0 * xv.x + wxf1 * xv.y;
    const float ag = gv.z + ebg_ + wxg0 * xv.x + wxg1 * xv.y;
    const float ao = gv.w + ebo_ + wxo0 * xv.x + wxo1 * xv.y;
    const float iv = sigm(ai), fv = sigm(af), gva = tanhf(ag), ov = sigm(ao);
    c = fv * c + iv * gva;
    const float hn = ov * tanhf(c);
    hsF[p ^ 1][(bA << 8) | uA] = hn;
    ((float*)encK4)[(((bG << 6) + (uA >> 2)) << 10) + (t << 2) + (uA & 3)] = hn;
    __syncthreads();                              // S_C: new h ready
    p ^= 1;
  }

  // ---------------- decoder: 256 steps, rotated schedule ----------------
  const float dbi_ = dBi[uA] + dBh[uA];
  const float dbf_ = dBi[256 + uA] + dBh[256 + uA];
  const float dbg_ = dBi[512 + uA] + dBh[512 + uA];
  const float dbo_ = dBi[768 + uA] + dBh[768 + uA];
  const float NEG_INF = __int_as_float((int)0xff800000);

  maskC[bA][uA] = 0;
  if (tid < 256) dinV[tid] = (v4f)0.f;
  __syncthreads();

  // ---- prologue: LSTM step 0 (din = 0 -> Wi contributes exact 0, skipped) ----
  {
    v4f a0 = (v4f)0.f, a1 = (v4f)0.f, a2 = (v4f)0.f, a3 = (v4f)0.f;
    const v4f* Wh = decWh4 + uP;
    const v4f* hq = (const v4f*)&hsF[p][0];
#pragma unroll 2
    for (int kk = 0; kk < 16; ++kk) {
      const int k4 = k4b + kk;
      const v4f w0 = Wh[(k4 * 4 + 0) << 8];
      const v4f w1 = Wh[(k4 * 4 + 1) << 8];
      const v4f w2 = Wh[(k4 * 4 + 2) << 8];
      const v4f w3 = Wh[(k4 * 4 + 3) << 8];
      const v4f h0 = hq[k4];
      const v4f h1 = hq[64 + k4];
      const v4f h2 = hq[128 + k4];
      const v4f h3 = hq[192 + k4];
      a0 += w0 * h0.x + w1 * h0.y + w2 * h0.z + w3 * h0.w;
      a1 += w0 * h1.x + w1 * h1.y + w2 * h1.z + w3 * h1.w;
      a2 += w0 * h2.x + w1 * h2.y + w2 * h2.z + w3 * h2.w;
      a3 += w0 * h3.x + w1 * h3.y + w2 * h3.z + w3 * h3.w;
    }
    red[(kq << 2) | 0][uP] = a0;
    red[(kq << 2) | 1][uP] = a1;
    red[(kq << 2) | 2][uP] = a2;
    red[(kq << 2) | 3][uP] = a3;
    __syncthreads();
    const v4f gv = red[bA][uA] + red[4 + bA][uA] + red[8 + bA][uA] + red[12 + bA][uA];
    const float iv = sigm(gv.x + dbi_), fv = sigm(gv.y + dbf_);
    const float gva = tanhf(gv.z + dbg_), ov = sigm(gv.w + dbo_);
    c = fv * c + iv * gva;
    const float hn = ov * tanhf(c);
    hsF[p ^ 1][(bA << 8) | uA] = hn;
    __syncthreads();
    p ^= 1;                                       // hsF[p] now holds h_0
  }

// ---- macro-expanded overlap phase: all indices literal -> registers ----
#define LOADC(DST, BASE)                                                      \
  DST.e0 = E[((BASE) + 0) << 8];                                              \
  DST.e1 = E[((BASE) + 1) << 8];                                              \
  DST.e2 = E[((BASE) + 2) << 8];                                              \
  DST.e3 = E[((BASE) + 3) << 8];

#define PHASE(PH, CUR, NXT)                                                   \
  {                                                                           \
    const int k4 = k4b + (PH);                                                \
    const v4f w0 = Wh[(k4 * 4 + 0) << 8];                                     \
    const v4f w1 = Wh[(k4 * 4 + 1) << 8];                                     \
    const v4f w2 = Wh[(k4 * 4 + 2) << 8];                                     \
    const v4f w3 = Wh[(k4 * 4 + 3) << 8];                                     \
    const v4f h0 = hq[k4];                                                    \
    const v4f h1 = hq[64 + k4];                                               \
    const v4f h2 = hq[128 + k4];                                              \
    const v4f h3 = hq[192 + k4];                                              \
    a0 += w0 * h0.x + w1 * h0.y + w2 * h0.z + w3 * h0.w;                      \
    a1 += w0 * h1.x + w1 * h1.y + w2 * h1.z + w3 * h1.w;                      \
    a2 += w0 * h2.x + w1 * h2.y + w2 * h2.z + w3 * h2.w;                      \
    a3 += w0 * h3.x + w1 * h3.y + w2 * h3.z + w3 * h3.w;                      \
  }                                                                           \
  if ((PH) < 14) {                                                            \
    if (!masked) { LOADC(NXT, ((PH) + 2) * 4) }                               \
  }                                                                           \
  if (!masked) {                                                              \
    {                                                                         \
      const v4f hv = hq2[(PH) * 4 + 0];                                       \
      sc += CUR.e0.x * hv.x + CUR.e0.y * hv.y + CUR.e0.z * hv.z + CUR.e0.w * hv.w; \
    }                                                                         \
    {                                                                         \
      const v4f hv = hq2[(PH) * 4 + 1];                                       \
      sc += CUR.e1.x * hv.x + CUR.e1.y * hv.y + CUR.e1.z * hv.z + CUR.e1.w * hv.w; \
    }                                                                         \
    {                                                                         \
      const v4f hv = hq2[(PH) * 4 + 2];                                       \
      sc += CUR.e2.x * hv.x + CUR.e2.y * hv.y + CUR.e2.z * hv.z + CUR.e2.w * hv.w; \
    }                                                                         \
    {                                                                         \
      const v4f hv = hq2[(PH) * 4 + 3];                                       \
      sc += CUR.e3.x * hv.x + CUR.e3.y * hv.y + CUR.e3.z * hv.z + CUR.e3.w * hv.w; \
    }                                                                         \
  }

  for (int t = 0; t < 256; ++t) {
    // ---- overlap: attn(t) loads+consume  ∥  Wh·h_t sweep (for t+1) ----
    const int masked = maskC[bA][uA];
    const v4f* E   = encK4 + (bG << 14) + uA;     // s = uA, step u4 via <<8
    const v4f* hq  = (const v4f*)&hsF[p][0];
    const v4f* hq2 = hq + (bA << 6);
    const v4f* Wh  = decWh4 + uP;
    v4f a0 = (v4f)0.f, a1 = (v4f)0.f, a2 = (v4f)0.f, a3 = (v4f)0.f;
    float sc = 0.f;
    chk cA, cB, cC;                                // 3 chunks, named -> VGPRs
    if (!masked) { LOADC(cA, 0) LOADC(cB, 4) }
    PHASE(0,  cA, cC) PHASE(1,  cB, cA) PHASE(2,  cC, cB)
    PHASE(3,  cA, cC) PHASE(4,  cB, cA) PHASE(5,  cC, cB)
    PHASE(6,  cA, cC) PHASE(7,  cB, cA) PHASE(8,  cC, cB)
    PHASE(9,  cA, cC) PHASE(10, cB, cA) PHASE(11, cC, cB)
    PHASE(12, cA, cC) PHASE(13, cB, cA) PHASE(14, cC, cB)
    PHASE(15, cA, cC)

    // ---- gumbel + argmax (thread (bA, s=uA)) ----
    unsigned bits;
    {
      unsigned kk0 = 0u, kk1 = (unsigned)t;
      tf2(0u, 42u, kk0, kk1);
      unsigned y0 = 0u, y1 = (unsigned)((bG << 8) + uA);
      tf2(kk0, kk1, y0, y1);
      bits = y0 ^ y1;
    }
    const float fr = __uint_as_float((bits >> 9) | 0x3f800000u) - 1.0f;
    const float uu = (fr > 0.f) ? fr : 1.17549435e-38f;
    const float gum = -logf(-logf(uu));
    float bv = masked ? NEG_INF : (sc + gum);
    int bi = uA;
#pragma unroll
    for (int off = 32; off; off >>= 1) {
      const float ov2 = __shfl_xor(bv, off, 64);
      const int oi2 = __shfl_xor(bi, off, 64);
      if (ov2 > bv || (ov2 == bv && oi2 < bi)) { bv = ov2; bi = oi2; }
    }
    if (l == 0) { partV[bA][uw] = bv; partI[bA][uw] = bi; }
    __syncthreads();                              // S_D: wave partials ready

    // final cross-chunk argmax, recomputed redundantly per thread
    float v = partV[bA][0]; int fi = partI[bA][0];
#pragma unroll
    for (int j = 1; j < 4; ++j) {
      const float vj = partV[bA][j];
      if (vj > v) { v = vj; fi = partI[bA][j]; }   // strict > keeps lowest s
    }
    if (uA == 0) out[(bG << 8) + t] = fi;
    if (uA == fi) maskC[bA][uA] = 1;
    if (tid < 256) {                               // stage din_{t+1}
      const int bb = tid >> 6, k4s = tid & 63;
      float v2 = partV[bb][0]; int fib = partI[bb][0];
#pragma unroll
      for (int j = 1; j < 4; ++j) {
        const float vj = partV[bb][j];
        if (vj > v2) { v2 = vj; fib = partI[bb][j]; }
      }
      dinV[tid] = encK4[((((b0 + bb) << 6) | k4s) << 8) + fib];
    }
    __syncthreads();                              // S_A: din/mask ready

    if (t == 255) break;                           // last index emitted

    // ---- Wi·din sweep (adds into the SAME a-regs, R4 order) ----
    {
      const v4f* Wi = decWi4 + uP;
#pragma unroll 2
      for (int kk = 0; kk < 16; ++kk) {
        const int k4 = k4b + kk;
        const v4f w0 = Wi[(k4 * 4 + 0) << 8];
        const v4f w1 = Wi[(k4 * 4 + 1) << 8];
        const v4f w2 = Wi[(k4 * 4 + 2) << 8];
        const v4f w3 = Wi[(k4 * 4 + 3) << 8];
        const v4f d0 = dinV[k4];
        const v4f d1 = dinV[64 + k4];
        const v4f d2 = dinV[128 + k4];
        const v4f d3 = dinV[192 + k4];
        a0 += w0 * d0.x + w1 * d0.y + w2 * d0.z + w3 * d0.w;
        a1 += w0 * d1.x + w1 * d1.y + w2 * d1.z + w3 * d1.w;
        a2 += w0 * d2.x + w1 * d2.y + w2 * d2.z + w3 * d2.w;
        a3 += w0 * d3.x + w1 * d3.y + w2 * d3.z + w3 * d3.w;
      }
    }
    red[(kq << 2) | 0][uP] = a0;
    red[(kq << 2) | 1][uP] = a1;
    red[(kq << 2) | 2][uP] = a2;
    red[(kq << 2) | 3][uP] = a3;
    __syncthreads();                              // S_B: partials ready

    // ---- P2: activation -> h_{t+1} ----
    const v4f gv = red[bA][uA] + red[4 + bA][uA] + red[8 + bA][uA] + red[12 + bA][uA];
    const float iv = sigm(gv.x + dbi_), fv = sigm(gv.y + dbf_);
    const float gva = tanhf(gv.z + dbg_), ov = sigm(gv.w + dbo_);
    c = fv * c + iv * gva;
    const float hn = ov * tanhf(c);
    hsF[p ^ 1][(bA << 8) | uA] = hn;
    __syncthreads();                              // S_C: new h ready
    p ^= 1;
  }
#undef PHASE
#undef LOADC
}

extern "C" void kernel_launch(void* const* d_in, const int* in_sizes, int n_in,
                              void* d_out, int out_size, void* d_ws, size_t ws_size,
                              hipStream_t stream) {
  (void)in_sizes; (void)n_in; (void)out_size;
  if (ws_size < WS_NEEDED) return;   // need ~139 MB scratch

  const float* inp = (const float*)d_in[0];
  const float* eWi = (const float*)d_in[1];
  const float* eWh = (const float*)d_in[2];
  const float* eBi = (const float*)d_in[3];
  const float* eBh = (const float*)d_in[4];
  const float* dWi = (const float*)d_in[5];
  const float* dWh = (const float*)d_in[6];
  const float* dBi = (const float*)d_in[7];
  const float* dBh = (const float*)d_in[8];
  int* out = (int*)d_out;
  float* wsf = (float*)d_ws;

  hipLaunchKernelGGL(repack_k, dim3(256), dim3(256), 0, stream, eWh, dWi, dWh, wsf);
  hipLaunchKernelGGL(ptrnet_kernel, dim3(128), dim3(1024), 0, stream,
                     inp, eWi, eBi, eBh, dBi, dBh, out, wsf);
}

// Round 5
// 79749.182 us; speedup vs baseline: 1.0214x; 1.0214x over previous
//
#include <hip/hip_runtime.h>
#include <cstdint>
#include <cstddef>

// ============================================================================
// PointerNet: encoder LSTM (B=512,S=256,D=2,H=256) + autoregressive pointer
// decode with jax.random.categorical (threefry2x32 partitionable, key 42).
// Output: int32 indices [512][256], trajectory-exact vs JAX reference.
//
// R9 = R8 + occupancy pin to 1 block/CU (the real spill fix).
// R6-R8 post-mortem: VGPR_Count pinned at 64 in ALL three despite launch
// bounds and named structs -> the AMDGPU backend budgets VGPRs from the
// LDS-derived achievable occupancy (79360B < 81920B -> 2 blocks/CU -> 8
// waves/EU -> 512/8 = 64 VGPRs) and spills the 48-reg attention pipeline to
// scratch (33MB footprint >> L2 -> 151GB HBM round-trip = the entire 80ms).
// launch_bounds' 2nd arg is only a MINIMUM waves/EU - it cannot lower the
// backend's occupancy target. Grid is 128 blocks on 256 CUs: 2 blocks/CU
// never happens anyway. Pin it two ways (both semantically inert):
//   (a) __attribute__((amdgpu_waves_per_eu(4,4))): max=4 waves/EU -> 128-reg
//       budget directly;
//   (b) red[16]->[17] rows: LDS 79360->83456B > 81920 -> LDS heuristic also
//       says 1 block/CU.
// Schedule unchanged from R6/R7/R8 (all PASSED, absmax 0):
//  * attn(t) encK4 loads (L3, ~600cy) issued+consumed interleaved with next
//    step's Wh.h sweep via macro-expanded 16-phase pipeline, 3 named chunk
//    structs (all literal indices), depth-2-ahead.
//  * 4 barriers/decoder step; FMA order identical to R4 -> exact trajectory.
// ============================================================================

typedef float v4f __attribute__((ext_vector_type(4)));

#define WS_ENCW4_OFF  (2u << 20)                    // [256 k][256 u][4 g] f32
#define WS_DECWI4_OFF (3u << 20)
#define WS_DECWH4_OFF (4u << 20)
#define WS_ENCK4_OFF  (5u << 20)                    // [512 b][64 u4][256 s][4] f32
#define WS_NEEDED     ((size_t)(5u << 20) + (size_t)512 * 64 * 256 * 16)

__device__ __forceinline__ unsigned rotl32(unsigned x, int r) {
  return (x << r) | (x >> (32 - r));
}
__device__ __forceinline__ float sigm(float x) { return 1.f / (1.f + expf(-x)); }

// Threefry-2x32, 20 rounds (jax._src.prng schedule) — verified exact R1-R8.
__device__ __forceinline__ void tf2(unsigned k0, unsigned k1,
                                    unsigned& x0, unsigned& x1) {
  const unsigned k2 = k0 ^ k1 ^ 0x1BD11BDAu;
  x0 += k0; x1 += k1;
  x0 += x1; x1 = rotl32(x1, 13); x1 ^= x0;
  x0 += x1; x1 = rotl32(x1, 15); x1 ^= x0;
  x0 += x1; x1 = rotl32(x1, 26); x1 ^= x0;
  x0 += x1; x1 = rotl32(x1,  6); x1 ^= x0;
  x0 += k1; x1 += k2 + 1u;
  x0 += x1; x1 = rotl32(x1, 17); x1 ^= x0;
  x0 += x1; x1 = rotl32(x1, 29); x1 ^= x0;
  x0 += x1; x1 = rotl32(x1, 16); x1 ^= x0;
  x0 += x1; x1 = rotl32(x1, 24); x1 ^= x0;
  x0 += k2; x1 += k0 + 2u;
  x0 += x1; x1 = rotl32(x1, 13); x1 ^= x0;
  x0 += x1; x1 = rotl32(x1, 15); x1 ^= x0;
  x0 += x1; x1 = rotl32(x1, 26); x1 ^= x0;
  x0 += x1; x1 = rotl32(x1,  6); x1 ^= x0;
  x0 += k0; x1 += k1 + 3u;
  x0 += x1; x1 = rotl32(x1, 17); x1 ^= x0;
  x0 += x1; x1 = rotl32(x1, 29); x1 ^= x0;
  x0 += x1; x1 = rotl32(x1, 16); x1 ^= x0;
  x0 += x1; x1 = rotl32(x1, 24); x1 ^= x0;
  x0 += k1; x1 += k2 + 4u;
  x0 += x1; x1 = rotl32(x1, 13); x1 ^= x0;
  x0 += x1; x1 = rotl32(x1, 15); x1 ^= x0;
  x0 += x1; x1 = rotl32(x1, 26); x1 ^= x0;
  x0 += x1; x1 = rotl32(x1,  6); x1 ^= x0;
  x0 += k2; x1 += k0 + 5u;
}

// Repack W [1024 rows][256 k] row-major -> [k][u][gate] (float4 per (k,u)).
__global__ void repack_k(const float* __restrict__ eWh,
                         const float* __restrict__ dWi,
                         const float* __restrict__ dWh,
                         float* __restrict__ ws) {
  float* encW4 = (float*)((char*)ws + WS_ENCW4_OFF);
  float* decWi4 = (float*)((char*)ws + WS_DECWI4_OFF);
  float* decWh4 = (float*)((char*)ws + WS_DECWH4_OFF);
  const int n = blockIdx.x * blockDim.x + threadIdx.x;   // 65536 = 256k x 256u
  if (n >= 65536) return;
  const int k = n >> 8, u = n & 255;
#pragma unroll
  for (int g = 0; g < 4; ++g) {
    const int src = ((g << 8) + u) * 256 + k;
    const int dst = (n << 2) + g;
    encW4[dst] = eWh[src];
    decWi4[dst] = dWi[src];
    decWh4[dst] = dWh[src];
  }
}

struct chk { v4f e0, e1, e2, e3; };                 // one 4-k4 attention chunk

__global__ void __launch_bounds__(1024)
__attribute__((amdgpu_waves_per_eu(4, 4)))          // pin 4 waves/EU -> 128-reg budget
ptrnet_kernel(const float* __restrict__ inp,    // [512][256][2]
              const float* __restrict__ eWi,    // [1024][2]
              const float* __restrict__ eBi, const float* __restrict__ eBh,
              const float* __restrict__ dBi, const float* __restrict__ dBh,
              int* __restrict__ out,            // [512][256]
              float* __restrict__ ws) {
  const int tid  = threadIdx.x;
  const int wave = tid >> 6, l = tid & 63;
  const int kq   = wave >> 2;               // K-quarter 0..3 (16 k4 each)
  const int uw   = wave & 3;                // u-slice 0..3
  const int uP   = (uw << 6) | l;           // this lane's unit in P1 (matmul)
  const int k4b  = kq << 4;
  const int bA   = tid >> 8;                // this thread's batch in P2/attn
  const int uA   = tid & 255;               // this thread's unit/score in P2/attn
  const int b0   = blockIdx.x << 2;
  const int bG   = b0 + bA;

  const v4f* encW4  = (const v4f*)((char*)ws + WS_ENCW4_OFF);
  const v4f* decWi4 = (const v4f*)((char*)ws + WS_DECWI4_OFF);
  const v4f* decWh4 = (const v4f*)((char*)ws + WS_DECWH4_OFF);
  v4f* encK4 = (v4f*)((char*)ws + WS_ENCK4_OFF);

  __shared__ __align__(16) float hsF[2][1024];   // h dbuf: [buf][b*256+u]
  __shared__ __align__(16) v4f dinV[256];        // dec_in [b][64 k4]
  // [17] not [16]: +4KB LDS pushes total past 81920B so the LDS-occupancy
  // heuristic also yields 1 block/CU (see header). Row 16 unused.
  __shared__ __align__(16) v4f red[17][256];     // partials [kq*4+b][u] (gates)
  __shared__ unsigned char maskC[4][256];
  __shared__ float partV[4][4];
  __shared__ int   partI[4][4];

  // ---- activation-thread constants (keyed by uA) ----
  const float ebi_ = eBi[uA] + eBh[uA];
  const float ebf_ = eBi[256 + uA] + eBh[256 + uA];
  const float ebg_ = eBi[512 + uA] + eBh[512 + uA];
  const float ebo_ = eBi[768 + uA] + eBh[768 + uA];
  const float wxi0 = eWi[2 * uA], wxi1 = eWi[2 * uA + 1];
  const float wxf0 = eWi[2 * (256 + uA)], wxf1 = eWi[2 * (256 + uA) + 1];
  const float wxg0 = eWi[2 * (512 + uA)], wxg1 = eWi[2 * (512 + uA) + 1];
  const float wxo0 = eWi[2 * (768 + uA)], wxo1 = eWi[2 * (768 + uA) + 1];

  hsF[0][tid] = 0.f;
  __syncthreads();

  float c = 0.f;        // cell state for (bG, uA) — register-resident throughout
  int p = 0;

  // ---------------- encoder: 256 steps (R4-exact) ----------------
  for (int t = 0; t < 256; ++t) {
    v4f a0 = (v4f)0.f, a1 = (v4f)0.f, a2 = (v4f)0.f, a3 = (v4f)0.f;
    const v4f* Wp = encW4 + uP;
    const v4f* hq = (const v4f*)&hsF[p][0];       // [4 b][64 k4]
#pragma unroll 2
    for (int kk = 0; kk < 16; ++kk) {
      const int k4 = k4b + kk;
      const v4f w0 = Wp[(k4 * 4 + 0) << 8];
      const v4f w1 = Wp[(k4 * 4 + 1) << 8];
      const v4f w2 = Wp[(k4 * 4 + 2) << 8];
      const v4f w3 = Wp[(k4 * 4 + 3) << 8];
      const v4f h0 = hq[k4];
      const v4f h1 = hq[64 + k4];
      const v4f h2 = hq[128 + k4];
      const v4f h3 = hq[192 + k4];
      a0 += w0 * h0.x + w1 * h0.y + w2 * h0.z + w3 * h0.w;
      a1 += w0 * h1.x + w1 * h1.y + w2 * h1.z + w3 * h1.w;
      a2 += w0 * h2.x + w1 * h2.y + w2 * h2.z + w3 * h2.w;
      a3 += w0 * h3.x + w1 * h3.y + w2 * h3.z + w3 * h3.w;
    }
    red[(kq << 2) | 0][uP] = a0;
    red[(kq << 2) | 1][uP] = a1;
    red[(kq << 2) | 2][uP] = a2;
    red[(kq << 2) | 3][uP] = a3;
    __syncthreads();                              // S_B: partials ready
    const v4f gv = red[bA][uA] + red[4 + bA][uA] + red[8 + bA][uA] + red[12 + bA][uA];
    const float2 xv = *(const float2*)(inp + (((bG) << 8) + t) * 2);
    const float ai = gv.x + ebi_ + wxi0 * xv.x + wxi1 * xv.y;
    const float af = gv.y + ebf_ + wxf0 * xv.x + wxf1 * xv.y;
    const float ag = gv.z + ebg_ + wxg0 * xv.x + wxg1 * xv.y;
    const float ao = gv.w + ebo_ + wxo0 * xv.x + wxo1 * xv.y;
    const float iv = sigm(ai), fv = sigm(af), gva = tanhf(ag), ov = sigm(ao);
    c = fv * c + iv * gva;
    const float hn = ov * tanhf(c);
    hsF[p ^ 1][(bA << 8) | uA] = hn;
    ((float*)encK4)[(((bG << 6) + (uA >> 2)) << 10) + (t << 2) + (uA & 3)] = hn;
    __syncthreads();                              // S_C: new h ready
    p ^= 1;
  }

  // ---------------- decoder: 256 steps, rotated schedule ----------------
  const float dbi_ = dBi[uA] + dBh[uA];
  const float dbf_ = dBi[256 + uA] + dBh[256 + uA];
  const float dbg_ = dBi[512 + uA] + dBh[512 + uA];
  const float dbo_ = dBi[768 + uA] + dBh[768 + uA];
  const float NEG_INF = __int_as_float((int)0xff800000);

  maskC[bA][uA] = 0;
  if (tid < 256) dinV[tid] = (v4f)0.f;
  __syncthreads();

  // ---- prologue: LSTM step 0 (din = 0 -> Wi contributes exact 0, skipped) ----
  {
    v4f a0 = (v4f)0.f, a1 = (v4f)0.f, a2 = (v4f)0.f, a3 = (v4f)0.f;
    const v4f* Wh = decWh4 + uP;
    const v4f* hq = (const v4f*)&hsF[p][0];
#pragma unroll 2
    for (int kk = 0; kk < 16; ++kk) {
      const int k4 = k4b + kk;
      const v4f w0 = Wh[(k4 * 4 + 0) << 8];
      const v4f w1 = Wh[(k4 * 4 + 1) << 8];
      const v4f w2 = Wh[(k4 * 4 + 2) << 8];
      const v4f w3 = Wh[(k4 * 4 + 3) << 8];
      const v4f h0 = hq[k4];
      const v4f h1 = hq[64 + k4];
      const v4f h2 = hq[128 + k4];
      const v4f h3 = hq[192 + k4];
      a0 += w0 * h0.x + w1 * h0.y + w2 * h0.z + w3 * h0.w;
      a1 += w0 * h1.x + w1 * h1.y + w2 * h1.z + w3 * h1.w;
      a2 += w0 * h2.x + w1 * h2.y + w2 * h2.z + w3 * h2.w;
      a3 += w0 * h3.x + w1 * h3.y + w2 * h3.z + w3 * h3.w;
    }
    red[(kq << 2) | 0][uP] = a0;
    red[(kq << 2) | 1][uP] = a1;
    red[(kq << 2) | 2][uP] = a2;
    red[(kq << 2) | 3][uP] = a3;
    __syncthreads();
    const v4f gv = red[bA][uA] + red[4 + bA][uA] + red[8 + bA][uA] + red[12 + bA][uA];
    const float iv = sigm(gv.x + dbi_), fv = sigm(gv.y + dbf_);
    const float gva = tanhf(gv.z + dbg_), ov = sigm(gv.w + dbo_);
    c = fv * c + iv * gva;
    const float hn = ov * tanhf(c);
    hsF[p ^ 1][(bA << 8) | uA] = hn;
    __syncthreads();
    p ^= 1;                                       // hsF[p] now holds h_0
  }

// ---- macro-expanded overlap phase: all indices literal -> registers ----
#define LOADC(DST, BASE)                                                      \
  DST.e0 = E[((BASE) + 0) << 8];                                              \
  DST.e1 = E[((BASE) + 1) << 8];                                              \
  DST.e2 = E[((BASE) + 2) << 8];                                              \
  DST.e3 = E[((BASE) + 3) << 8];

#define PHASE(PH, CUR, NXT)                                                   \
  {                                                                           \
    const int k4 = k4b + (PH);                                                \
    const v4f w0 = Wh[(k4 * 4 + 0) << 8];                                     \
    const v4f w1 = Wh[(k4 * 4 + 1) << 8];                                     \
    const v4f w2 = Wh[(k4 * 4 + 2) << 8];                                     \
    const v4f w3 = Wh[(k4 * 4 + 3) << 8];                                     \
    const v4f h0 = hq[k4];                                                    \
    const v4f h1 = hq[64 + k4];                                               \
    const v4f h2 = hq[128 + k4];                                              \
    const v4f h3 = hq[192 + k4];                                              \
    a0 += w0 * h0.x + w1 * h0.y + w2 * h0.z + w3 * h0.w;                      \
    a1 += w0 * h1.x + w1 * h1.y + w2 * h1.z + w3 * h1.w;                      \
    a2 += w0 * h2.x + w1 * h2.y + w2 * h2.z + w3 * h2.w;                      \
    a3 += w0 * h3.x + w1 * h3.y + w2 * h3.z + w3 * h3.w;                      \
  }                                                                           \
  if ((PH) < 14) {                                                            \
    if (!masked) { LOADC(NXT, ((PH) + 2) * 4) }                               \
  }                                                                           \
  if (!masked) {                                                              \
    {                                                                         \
      const v4f hv = hq2[(PH) * 4 + 0];                                       \
      sc += CUR.e0.x * hv.x + CUR.e0.y * hv.y + CUR.e0.z * hv.z + CUR.e0.w * hv.w; \
    }                                                                         \
    {                                                                         \
      const v4f hv = hq2[(PH) * 4 + 1];                                       \
      sc += CUR.e1.x * hv.x + CUR.e1.y * hv.y + CUR.e1.z * hv.z + CUR.e1.w * hv.w; \
    }                                                                         \
    {                                                                         \
      const v4f hv = hq2[(PH) * 4 + 2];                                       \
      sc += CUR.e2.x * hv.x + CUR.e2.y * hv.y + CUR.e2.z * hv.z + CUR.e2.w * hv.w; \
    }                                                                         \
    {                                                                         \
      const v4f hv = hq2[(PH) * 4 + 3];                                       \
      sc += CUR.e3.x * hv.x + CUR.e3.y * hv.y + CUR.e3.z * hv.z + CUR.e3.w * hv.w; \
    }                                                                         \
  }

  for (int t = 0; t < 256; ++t) {
    // ---- overlap: attn(t) loads+consume  ∥  Wh·h_t sweep (for t+1) ----
    const int masked = maskC[bA][uA];
    const v4f* E   = encK4 + (bG << 14) + uA;     // s = uA, step u4 via <<8
    const v4f* hq  = (const v4f*)&hsF[p][0];
    const v4f* hq2 = hq + (bA << 6);
    const v4f* Wh  = decWh4 + uP;
    v4f a0 = (v4f)0.f, a1 = (v4f)0.f, a2 = (v4f)0.f, a3 = (v4f)0.f;
    float sc = 0.f;
    chk cA, cB, cC;                                // 3 chunks, named -> VGPRs
    if (!masked) { LOADC(cA, 0) LOADC(cB, 4) }
    PHASE(0,  cA, cC) PHASE(1,  cB, cA) PHASE(2,  cC, cB)
    PHASE(3,  cA, cC) PHASE(4,  cB, cA) PHASE(5,  cC, cB)
    PHASE(6,  cA, cC) PHASE(7,  cB, cA) PHASE(8,  cC, cB)
    PHASE(9,  cA, cC) PHASE(10, cB, cA) PHASE(11, cC, cB)
    PHASE(12, cA, cC) PHASE(13, cB, cA) PHASE(14, cC, cB)
    PHASE(15, cA, cC)

    // ---- gumbel + argmax (thread (bA, s=uA)) ----
    unsigned bits;
    {
      unsigned kk0 = 0u, kk1 = (unsigned)t;
      tf2(0u, 42u, kk0, kk1);
      unsigned y0 = 0u, y1 = (unsigned)((bG << 8) + uA);
      tf2(kk0, kk1, y0, y1);
      bits = y0 ^ y1;
    }
    const float fr = __uint_as_float((bits >> 9) | 0x3f800000u) - 1.0f;
    const float uu = (fr > 0.f) ? fr : 1.17549435e-38f;
    const float gum = -logf(-logf(uu));
    float bv = masked ? NEG_INF : (sc + gum);
    int bi = uA;
#pragma unroll
    for (int off = 32; off; off >>= 1) {
      const float ov2 = __shfl_xor(bv, off, 64);
      const int oi2 = __shfl_xor(bi, off, 64);
      if (ov2 > bv || (ov2 == bv && oi2 < bi)) { bv = ov2; bi = oi2; }
    }
    if (l == 0) { partV[bA][uw] = bv; partI[bA][uw] = bi; }
    __syncthreads();                              // S_D: wave partials ready

    // final cross-chunk argmax, recomputed redundantly per thread
    float v = partV[bA][0]; int fi = partI[bA][0];
#pragma unroll
    for (int j = 1; j < 4; ++j) {
      const float vj = partV[bA][j];
      if (vj > v) { v = vj; fi = partI[bA][j]; }   // strict > keeps lowest s
    }
    if (uA == 0) out[(bG << 8) + t] = fi;
    if (uA == fi) maskC[bA][uA] = 1;
    if (tid < 256) {                               // stage din_{t+1}
      const int bb = tid >> 6, k4s = tid & 63;
      float v2 = partV[bb][0]; int fib = partI[bb][0];
#pragma unroll
      for (int j = 1; j < 4; ++j) {
        const float vj = partV[bb][j];
        if (vj > v2) { v2 = vj; fib = partI[bb][j]; }
      }
      dinV[tid] = encK4[((((b0 + bb) << 6) | k4s) << 8) + fib];
    }
    __syncthreads();                              // S_A: din/mask ready

    if (t == 255) break;                           // last index emitted

    // ---- Wi·din sweep (adds into the SAME a-regs, R4 order) ----
    {
      const v4f* Wi = decWi4 + uP;
#pragma unroll 2
      for (int kk = 0; kk < 16; ++kk) {
        const int k4 = k4b + kk;
        const v4f w0 = Wi[(k4 * 4 + 0) << 8];
        const v4f w1 = Wi[(k4 * 4 + 1) << 8];
        const v4f w2 = Wi[(k4 * 4 + 2) << 8];
        const v4f w3 = Wi[(k4 * 4 + 3) << 8];
        const v4f d0 = dinV[k4];
        const v4f d1 = dinV[64 + k4];
        const v4f d2 = dinV[128 + k4];
        const v4f d3 = dinV[192 + k4];
        a0 += w0 * d0.x + w1 * d0.y + w2 * d0.z + w3 * d0.w;
        a1 += w0 * d1.x + w1 * d1.y + w2 * d1.z + w3 * d1.w;
        a2 += w0 * d2.x + w1 * d2.y + w2 * d2.z + w3 * d2.w;
        a3 += w0 * d3.x + w1 * d3.y + w2 * d3.z + w3 * d3.w;
      }
    }
    red[(kq << 2) | 0][uP] = a0;
    red[(kq << 2) | 1][uP] = a1;
    red[(kq << 2) | 2][uP] = a2;
    red[(kq << 2) | 3][uP] = a3;
    __syncthreads();                              // S_B: partials ready

    // ---- P2: activation -> h_{t+1} ----
    const v4f gv = red[bA][uA] + red[4 + bA][uA] + red[8 + bA][uA] + red[12 + bA][uA];
    const float iv = sigm(gv.x + dbi_), fv = sigm(gv.y + dbf_);
    const float gva = tanhf(gv.z + dbg_), ov = sigm(gv.w + dbo_);
    c = fv * c + iv * gva;
    const float hn = ov * tanhf(c);
    hsF[p ^ 1][(bA << 8) | uA] = hn;
    __syncthreads();                              // S_C: new h ready
    p ^= 1;
  }
#undef PHASE
#undef LOADC
}

extern "C" void kernel_launch(void* const* d_in, const int* in_sizes, int n_in,
                              void* d_out, int out_size, void* d_ws, size_t ws_size,
                              hipStream_t stream) {
  (void)in_sizes; (void)n_in; (void)out_size;
  if (ws_size < WS_NEEDED) return;   // need ~139 MB scratch

  const float* inp = (const float*)d_in[0];
  const float* eWi = (const float*)d_in[1];
  const float* eWh = (const float*)d_in[2];
  const float* eBi = (const float*)d_in[3];
  const float* eBh = (const float*)d_in[4];
  const float* dWi = (const float*)d_in[5];
  const float* dWh = (const float*)d_in[6];
  const float* dBi = (const float*)d_in[7];
  const float* dBh = (const float*)d_in[8];
  int* out = (int*)d_out;
  float* wsf = (float*)d_ws;

  hipLaunchKernelGGL(repack_k, dim3(256), dim3(256), 0, stream, eWh, dWi, dWh, wsf);
  hipLaunchKernelGGL(ptrnet_kernel, dim3(128), dim3(1024), 0, stream,
                     inp, eWi, eBi, eBh, dBi, dBh, out, wsf);
}

// Round 6
// 11730.503 us; speedup vs baseline: 6.9439x; 6.7984x over previous
//
#include <hip/hip_runtime.h>
#include <cstdint>
#include <cstddef>

// ============================================================================
// PointerNet: encoder LSTM (B=512,S=256,D=2,H=256) + autoregressive pointer
// decode with jax.random.categorical (threefry2x32 partitionable, key 42).
// Output: int32 indices [512][256], trajectory-exact vs JAX reference.
//
// R10 = R4 (best verified, 11752us) + the 4-barrier staging merge (verified
// in R5-R9). R6-R9 post-mortem: the register-pipelined attn/Wh overlap is
// unimplementable -- the backend pins this kernel at 64 VGPRs regardless of
// __launch_bounds__(1024,4), amdgpu_waves_per_eu(4,4), LDS>80KB, or fully
// static indexing, and spills any added pipeline state to scratch (75GB of
// scratch traffic, 80ms). Reverted to the exact R4 compiler context (bare
// launch_bounds, red[16], 79360B LDS -> 64 VGPR, no spill).
//
// Structure: grid = 128 blocks x 1024 threads, 4 batches per block.
// Waves partition (K-quarter x u-slice) for the gate matmuls; weight float4s
// read once per block per sweep (L2-resident); thread (b,u) owns activation
// + cell state c in a register for the whole kernel. Decoder: 4 barriers per
// step (S_B partials, S_C h, S_D argmax partials, S_A din/mask) -- din is
// staged from partV/partI recompute, no idxS round-trip (R5 merge).
// ============================================================================

typedef float v4f __attribute__((ext_vector_type(4)));

#define WS_ENCW4_OFF  (2u << 20)                    // [256 k][256 u][4 g] f32
#define WS_DECWI4_OFF (3u << 20)
#define WS_DECWH4_OFF (4u << 20)
#define WS_ENCK4_OFF  (5u << 20)                    // [512 b][64 u4][256 s][4] f32
#define WS_NEEDED     ((size_t)(5u << 20) + (size_t)512 * 64 * 256 * 16)

__device__ __forceinline__ unsigned rotl32(unsigned x, int r) {
  return (x << r) | (x >> (32 - r));
}
__device__ __forceinline__ float sigm(float x) { return 1.f / (1.f + expf(-x)); }

// Threefry-2x32, 20 rounds (jax._src.prng schedule) — verified exact R1-R9.
__device__ __forceinline__ void tf2(unsigned k0, unsigned k1,
                                    unsigned& x0, unsigned& x1) {
  const unsigned k2 = k0 ^ k1 ^ 0x1BD11BDAu;
  x0 += k0; x1 += k1;
  x0 += x1; x1 = rotl32(x1, 13); x1 ^= x0;
  x0 += x1; x1 = rotl32(x1, 15); x1 ^= x0;
  x0 += x1; x1 = rotl32(x1, 26); x1 ^= x0;
  x0 += x1; x1 = rotl32(x1,  6); x1 ^= x0;
  x0 += k1; x1 += k2 + 1u;
  x0 += x1; x1 = rotl32(x1, 17); x1 ^= x0;
  x0 += x1; x1 = rotl32(x1, 29); x1 ^= x0;
  x0 += x1; x1 = rotl32(x1, 16); x1 ^= x0;
  x0 += x1; x1 = rotl32(x1, 24); x1 ^= x0;
  x0 += k2; x1 += k0 + 2u;
  x0 += x1; x1 = rotl32(x1, 13); x1 ^= x0;
  x0 += x1; x1 = rotl32(x1, 15); x1 ^= x0;
  x0 += x1; x1 = rotl32(x1, 26); x1 ^= x0;
  x0 += x1; x1 = rotl32(x1,  6); x1 ^= x0;
  x0 += k0; x1 += k1 + 3u;
  x0 += x1; x1 = rotl32(x1, 17); x1 ^= x0;
  x0 += x1; x1 = rotl32(x1, 29); x1 ^= x0;
  x0 += x1; x1 = rotl32(x1, 16); x1 ^= x0;
  x0 += x1; x1 = rotl32(x1, 24); x1 ^= x0;
  x0 += k1; x1 += k2 + 4u;
  x0 += x1; x1 = rotl32(x1, 13); x1 ^= x0;
  x0 += x1; x1 = rotl32(x1, 15); x1 ^= x0;
  x0 += x1; x1 = rotl32(x1, 26); x1 ^= x0;
  x0 += x1; x1 = rotl32(x1,  6); x1 ^= x0;
  x0 += k2; x1 += k0 + 5u;
}

// Repack W [1024 rows][256 k] row-major -> [k][u][gate] (float4 per (k,u)).
__global__ void repack_k(const float* __restrict__ eWh,
                         const float* __restrict__ dWi,
                         const float* __restrict__ dWh,
                         float* __restrict__ ws) {
  float* encW4 = (float*)((char*)ws + WS_ENCW4_OFF);
  float* decWi4 = (float*)((char*)ws + WS_DECWI4_OFF);
  float* decWh4 = (float*)((char*)ws + WS_DECWH4_OFF);
  const int n = blockIdx.x * blockDim.x + threadIdx.x;   // 65536 = 256k x 256u
  if (n >= 65536) return;
  const int k = n >> 8, u = n & 255;
#pragma unroll
  for (int g = 0; g < 4; ++g) {
    const int src = ((g << 8) + u) * 256 + k;
    const int dst = (n << 2) + g;
    encW4[dst] = eWh[src];
    decWi4[dst] = dWi[src];
    decWh4[dst] = dWh[src];
  }
}

__global__ void __launch_bounds__(1024)
ptrnet_kernel(const float* __restrict__ inp,    // [512][256][2]
              const float* __restrict__ eWi,    // [1024][2]
              const float* __restrict__ eBi, const float* __restrict__ eBh,
              const float* __restrict__ dBi, const float* __restrict__ dBh,
              int* __restrict__ out,            // [512][256]
              float* __restrict__ ws) {
  const int tid  = threadIdx.x;
  const int wave = tid >> 6, l = tid & 63;
  const int kq   = wave >> 2;               // K-quarter 0..3 (16 k4 each)
  const int uw   = wave & 3;                // u-slice 0..3
  const int uP   = (uw << 6) | l;           // this lane's unit in P1 (matmul)
  const int k4b  = kq << 4;
  const int bA   = tid >> 8;                // this thread's batch in P2/attn
  const int uA   = tid & 255;               // this thread's unit/score in P2/attn
  const int b0   = blockIdx.x << 2;
  const int bG   = b0 + bA;

  const v4f* encW4  = (const v4f*)((char*)ws + WS_ENCW4_OFF);
  const v4f* decWi4 = (const v4f*)((char*)ws + WS_DECWI4_OFF);
  const v4f* decWh4 = (const v4f*)((char*)ws + WS_DECWH4_OFF);
  v4f* encK4 = (v4f*)((char*)ws + WS_ENCK4_OFF);

  __shared__ __align__(16) float hsF[2][1024];   // h dbuf: [buf][b*256+u]
  __shared__ __align__(16) v4f dinV[256];        // dec_in [b][64 k4]
  __shared__ __align__(16) v4f red[16][256];     // partials [kq*4+b][u] (gates)
  __shared__ unsigned char maskC[4][256];
  __shared__ float partV[4][4];
  __shared__ int   partI[4][4];

  // ---- activation-thread constants (keyed by uA) ----
  const float ebi_ = eBi[uA] + eBh[uA];
  const float ebf_ = eBi[256 + uA] + eBh[256 + uA];
  const float ebg_ = eBi[512 + uA] + eBh[512 + uA];
  const float ebo_ = eBi[768 + uA] + eBh[768 + uA];
  const float wxi0 = eWi[2 * uA], wxi1 = eWi[2 * uA + 1];
  const float wxf0 = eWi[2 * (256 + uA)], wxf1 = eWi[2 * (256 + uA) + 1];
  const float wxg0 = eWi[2 * (512 + uA)], wxg1 = eWi[2 * (512 + uA) + 1];
  const float wxo0 = eWi[2 * (768 + uA)], wxo1 = eWi[2 * (768 + uA) + 1];

  hsF[0][tid] = 0.f;
  __syncthreads();

  float c = 0.f;        // cell state for (bG, uA) — register-resident throughout
  int p = 0;

  // ---------------- encoder: 256 steps (R4-exact) ----------------
  for (int t = 0; t < 256; ++t) {
    // P1: Wh·h partials for this (kq, u) over all 4 batches
    v4f a0 = (v4f)0.f, a1 = (v4f)0.f, a2 = (v4f)0.f, a3 = (v4f)0.f;
    const v4f* Wp = encW4 + uP;
    const v4f* hq = (const v4f*)&hsF[p][0];       // [4 b][64 k4]
#pragma unroll 2
    for (int kk = 0; kk < 16; ++kk) {
      const int k4 = k4b + kk;
      const v4f w0 = Wp[(k4 * 4 + 0) << 8];
      const v4f w1 = Wp[(k4 * 4 + 1) << 8];
      const v4f w2 = Wp[(k4 * 4 + 2) << 8];
      const v4f w3 = Wp[(k4 * 4 + 3) << 8];
      const v4f h0 = hq[k4];
      const v4f h1 = hq[64 + k4];
      const v4f h2 = hq[128 + k4];
      const v4f h3 = hq[192 + k4];
      a0 += w0 * h0.x + w1 * h0.y + w2 * h0.z + w3 * h0.w;
      a1 += w0 * h1.x + w1 * h1.y + w2 * h1.z + w3 * h1.w;
      a2 += w0 * h2.x + w1 * h2.y + w2 * h2.z + w3 * h2.w;
      a3 += w0 * h3.x + w1 * h3.y + w2 * h3.z + w3 * h3.w;
    }
    red[(kq << 2) | 0][uP] = a0;
    red[(kq << 2) | 1][uP] = a1;
    red[(kq << 2) | 2][uP] = a2;
    red[(kq << 2) | 3][uP] = a3;
    __syncthreads();                              // S_B: partials ready
    // P2: activation for (bA, uA)
    const v4f gv = red[bA][uA] + red[4 + bA][uA] + red[8 + bA][uA] + red[12 + bA][uA];
    const float2 xv = *(const float2*)(inp + (((bG) << 8) + t) * 2);
    const float ai = gv.x + ebi_ + wxi0 * xv.x + wxi1 * xv.y;
    const float af = gv.y + ebf_ + wxf0 * xv.x + wxf1 * xv.y;
    const float ag = gv.z + ebg_ + wxg0 * xv.x + wxg1 * xv.y;
    const float ao = gv.w + ebo_ + wxo0 * xv.x + wxo1 * xv.y;
    const float iv = sigm(ai), fv = sigm(af), gva = tanhf(ag), ov = sigm(ao);
    c = fv * c + iv * gva;
    const float hn = ov * tanhf(c);
    hsF[p ^ 1][(bA << 8) | uA] = hn;
    ((float*)encK4)[(((bG << 6) + (uA >> 2)) << 10) + (t << 2) + (uA & 3)] = hn;
    __syncthreads();                              // S_C: new h ready
    p ^= 1;
  }

  // ---------------- decoder: 256 steps ----------------
  const float dbi_ = dBi[uA] + dBh[uA];
  const float dbf_ = dBi[256 + uA] + dBh[256 + uA];
  const float dbg_ = dBi[512 + uA] + dBh[512 + uA];
  const float dbo_ = dBi[768 + uA] + dBh[768 + uA];
  const float NEG_INF = __int_as_float((int)0xff800000);

  maskC[bA][uA] = 0;
  if (tid < 256) dinV[tid] = (v4f)0.f;            // dec_in(t=0) = 0
  __syncthreads();

  for (int t = 0; t < 256; ++t) {
    // P1: Wh·h + Wi·din partials (two sweeps keep VGPR pressure low)
    v4f a0 = (v4f)0.f, a1 = (v4f)0.f, a2 = (v4f)0.f, a3 = (v4f)0.f;
    {
      const v4f* Wh = decWh4 + uP;
      const v4f* hq = (const v4f*)&hsF[p][0];
#pragma unroll 2
      for (int kk = 0; kk < 16; ++kk) {
        const int k4 = k4b + kk;
        const v4f w0 = Wh[(k4 * 4 + 0) << 8];
        const v4f w1 = Wh[(k4 * 4 + 1) << 8];
        const v4f w2 = Wh[(k4 * 4 + 2) << 8];
        const v4f w3 = Wh[(k4 * 4 + 3) << 8];
        const v4f h0 = hq[k4];
        const v4f h1 = hq[64 + k4];
        const v4f h2 = hq[128 + k4];
        const v4f h3 = hq[192 + k4];
        a0 += w0 * h0.x + w1 * h0.y + w2 * h0.z + w3 * h0.w;
        a1 += w0 * h1.x + w1 * h1.y + w2 * h1.z + w3 * h1.w;
        a2 += w0 * h2.x + w1 * h2.y + w2 * h2.z + w3 * h2.w;
        a3 += w0 * h3.x + w1 * h3.y + w2 * h3.z + w3 * h3.w;
      }
    }
    {
      const v4f* Wi = decWi4 + uP;
#pragma unroll 2
      for (int kk = 0; kk < 16; ++kk) {
        const int k4 = k4b + kk;
        const v4f w0 = Wi[(k4 * 4 + 0) << 8];
        const v4f w1 = Wi[(k4 * 4 + 1) << 8];
        const v4f w2 = Wi[(k4 * 4 + 2) << 8];
        const v4f w3 = Wi[(k4 * 4 + 3) << 8];
        const v4f d0 = dinV[k4];
        const v4f d1 = dinV[64 + k4];
        const v4f d2 = dinV[128 + k4];
        const v4f d3 = dinV[192 + k4];
        a0 += w0 * d0.x + w1 * d0.y + w2 * d0.z + w3 * d0.w;
        a1 += w0 * d1.x + w1 * d1.y + w2 * d1.z + w3 * d1.w;
        a2 += w0 * d2.x + w1 * d2.y + w2 * d2.z + w3 * d2.w;
        a3 += w0 * d3.x + w1 * d3.y + w2 * d3.z + w3 * d3.w;
      }
    }
    red[(kq << 2) | 0][uP] = a0;
    red[(kq << 2) | 1][uP] = a1;
    red[(kq << 2) | 2][uP] = a2;
    red[(kq << 2) | 3][uP] = a3;
    __syncthreads();                              // S_B: partials ready

    // P2: activation for (bA, uA)
    const v4f gv = red[bA][uA] + red[4 + bA][uA] + red[8 + bA][uA] + red[12 + bA][uA];
    const float ai = gv.x + dbi_;
    const float af = gv.y + dbf_;
    const float ag = gv.z + dbg_;
    const float ao = gv.w + dbo_;
    const float iv = sigm(ai), fv = sigm(af), gva = tanhf(ag), ov = sigm(ao);
    c = fv * c + iv * gva;
    const float hn = ov * tanhf(c);
    hsF[p ^ 1][(bA << 8) | uA] = hn;
    __syncthreads();                              // S_C: new h ready
    p ^= 1;

    // attention + gumbel sampling: thread (bA, s=uA)
    const int s = uA;
    const int masked = maskC[bA][s];
    float sc = 0.f;
    if (!masked) {
      const v4f* E = encK4 + (bG << 14) + s;
      const v4f* hq2 = ((const v4f*)&hsF[p][0]) + (bA << 6);
#pragma unroll 4
      for (int k4 = 0; k4 < 64; ++k4) {
        const v4f ev = E[k4 << 8];
        const v4f hv = hq2[k4];
        sc += ev.x * hv.x + ev.y * hv.y + ev.z * hv.z + ev.w * hv.w;
      }
    }
    // threefry2x32 partitionable: key_t = tf2(key42; 0,t); bits = x0^x1
    unsigned bits;
    {
      unsigned kk0 = 0u, kk1 = (unsigned)t;
      tf2(0u, 42u, kk0, kk1);
      unsigned y0 = 0u, y1 = (unsigned)((bG << 8) + s);
      tf2(kk0, kk1, y0, y1);
      bits = y0 ^ y1;
    }
    const float fr = __uint_as_float((bits >> 9) | 0x3f800000u) - 1.0f;
    const float uu = (fr > 0.f) ? fr : 1.17549435e-38f;
    const float gum = -logf(-logf(uu));
    float bv = masked ? NEG_INF : (sc + gum);
    int bi = s;
    // wave argmax, first-index tie-break (matches jnp.argmax)
#pragma unroll
    for (int off = 32; off; off >>= 1) {
      const float ov2 = __shfl_xor(bv, off, 64);
      const int oi2 = __shfl_xor(bi, off, 64);
      if (ov2 > bv || (ov2 == bv && oi2 < bi)) { bv = ov2; bi = oi2; }
    }
    if (l == 0) { partV[bA][uw] = bv; partI[bA][uw] = bi; }
    __syncthreads();                              // S_D: wave partials ready

    // final cross-chunk argmax, computed redundantly by all threads of batch
    float v = partV[bA][0]; int fi = partI[bA][0];
#pragma unroll
    for (int j = 1; j < 4; ++j) {
      const float vj = partV[bA][j];
      if (vj > v) { v = vj; fi = partI[bA][j]; }   // strict > keeps lowest s
    }
    if (uA == 0) out[(bG << 8) + t] = fi;
    if (uA == fi) maskC[bA][uA] = 1;
    // stage next dec_in directly: staging thread recomputes argmax for ITS
    // batch bb from partV/partI (no idxS round-trip, saves one barrier)
    if (tid < 256) {
      const int bb = tid >> 6, k4s = tid & 63;
      float v2 = partV[bb][0]; int fib = partI[bb][0];
#pragma unroll
      for (int j = 1; j < 4; ++j) {
        const float vj = partV[bb][j];
        if (vj > v2) { v2 = vj; fib = partI[bb][j]; }
      }
      dinV[tid] = encK4[((((b0 + bb) << 6) | k4s) << 8) + fib];
    }
    __syncthreads();                              // S_A: din/mask ready
  }
}

extern "C" void kernel_launch(void* const* d_in, const int* in_sizes, int n_in,
                              void* d_out, int out_size, void* d_ws, size_t ws_size,
                              hipStream_t stream) {
  (void)in_sizes; (void)n_in; (void)out_size;
  if (ws_size < WS_NEEDED) return;   // need ~139 MB scratch

  const float* inp = (const float*)d_in[0];
  const float* eWi = (const float*)d_in[1];
  const float* eWh = (const float*)d_in[2];
  const float* eBi = (const float*)d_in[3];
  const float* eBh = (const float*)d_in[4];
  const float* dWi = (const float*)d_in[5];
  const float* dWh = (const float*)d_in[6];
  const float* dBi = (const float*)d_in[7];
  const float* dBh = (const float*)d_in[8];
  int* out = (int*)d_out;
  float* wsf = (float*)d_ws;

  hipLaunchKernelGGL(repack_k, dim3(256), dim3(256), 0, stream, eWh, dWi, dWh, wsf);
  hipLaunchKernelGGL(ptrnet_kernel, dim3(128), dim3(1024), 0, stream,
                     inp, eWi, eBi, eBh, dBi, dBh, out, wsf);
}